// Round 5
// baseline (36.118 us; speedup 1.0000x reference)
//
#include <hip/hip_runtime.h>
#include <math.h>

#define HH 30
#define WWID 30
#define HW 900
#define SENTV 900
#define DD 256
#define MAXK 16
#define A_LD 264

#define COMP(v, jj) ((jj) == 0 ? (v).x : (jj) == 1 ? (v).y : (jj) == 2 ? (v).z : (v).w)

__device__ __forceinline__ float gelu_exact(float x) {
    return 0.5f * x * (1.0f + erff(x * 0.70710678118654752440f));
}

// Split-K GEMM phase: wave wv owns k in [32wv, 32wv+32), 8 rows x 4 cols/thread.
// Software-pipelined: chunk c+1's 8 weight float4s issued before chunk c's FMAs.
__device__ __forceinline__ void gemm_phase(
    const float (* __restrict__ Asrc)[A_LD],
    const float* __restrict__ Wm,
    float (* __restrict__ part)[8][DD],
    int wv, int c0)
{
    const int kbase = wv * 32;
    float acc[8][4];
    #pragma unroll
    for (int r = 0; r < 8; ++r) { acc[r][0] = 0.f; acc[r][1] = 0.f; acc[r][2] = 0.f; acc[r][3] = 0.f; }

    const float* wp = Wm + (size_t)kbase * DD + c0;
    float4 wc[8], wn[8];
    #pragma unroll
    for (int j = 0; j < 8; ++j) wc[j] = *(const float4*)(wp + (size_t)j * DD);

    #pragma unroll
    for (int ch = 0; ch < 4; ++ch) {
        if (ch < 3) {   // prefetch next weight chunk
            const float* wpn = wp + (size_t)((ch + 1) * 8) * DD;
            #pragma unroll
            for (int j = 0; j < 8; ++j) wn[j] = *(const float4*)(wpn + (size_t)j * DD);
        }
        float4 aA[8], aB[8];
        #pragma unroll
        for (int r = 0; r < 8; ++r) {
            aA[r] = *(const float4*)(&Asrc[r][kbase + ch * 8]);
            aB[r] = *(const float4*)(&Asrc[r][kbase + ch * 8 + 4]);
        }
        #pragma unroll
        for (int j = 0; j < 4; ++j) {
            #pragma unroll
            for (int r = 0; r < 8; ++r) {
                float av = COMP(aA[r], j);
                acc[r][0] += av * wc[j].x;
                acc[r][1] += av * wc[j].y;
                acc[r][2] += av * wc[j].z;
                acc[r][3] += av * wc[j].w;
            }
        }
        #pragma unroll
        for (int j = 0; j < 4; ++j) {
            #pragma unroll
            for (int r = 0; r < 8; ++r) {
                float av = COMP(aB[r], j);
                acc[r][0] += av * wc[4 + j].x;
                acc[r][1] += av * wc[4 + j].y;
                acc[r][2] += av * wc[4 + j].z;
                acc[r][3] += av * wc[4 + j].w;
            }
        }
        if (ch < 3) {
            #pragma unroll
            for (int j = 0; j < 8; ++j) wc[j] = wn[j];
        }
    }

    if (wv < 4) {
        #pragma unroll
        for (int r = 0; r < 8; ++r)
            *(float4*)(&part[wv][r][c0]) = make_float4(acc[r][0], acc[r][1], acc[r][2], acc[r][3]);
    }
    __syncthreads();
    if (wv >= 4) {
        #pragma unroll
        for (int r = 0; r < 8; ++r) {
            float4 p = *(const float4*)(&part[wv - 4][r][c0]);
            p.x += acc[r][0]; p.y += acc[r][1]; p.z += acc[r][2]; p.w += acc[r][3];
            *(float4*)(&part[wv - 4][r][c0]) = p;
        }
    }
    __syncthreads();
}

// ======================= K1: prep (CCL + bbox + pooling + sn) ================
__global__ __launch_bounds__(512) void ccce_prep(
    const float* __restrict__ grid_emb,
    const int* __restrict__ grid,
    const float* __restrict__ structure_rep,
    float* __restrict__ comb_ws,   // [B][16][A_LD]
    float* __restrict__ sn_ws,     // [B][256]
    int* __restrict__ sval_ws,     // [B][16]
    int KS)
{
    const int b   = blockIdx.x;
    const int tid = threadIdx.x;
    const int tx  = tid & 63;
    const int wv  = tid >> 6;
    const int c0  = tx * 4;

    __shared__ int color_s[HW];
    __shared__ int lab_s[HW];
    __shared__ int changed_s;
    __shared__ int root_s[MAXK];
    __shared__ int nroot_s;
    __shared__ int by0[MAXK], by1[MAXK], bx0[MAXK], bx1[MAXK];
    __shared__ int sy[MAXK], sx[MAXK], shh[MAXK], sww[MAXK], scol[MAXK], sval[MAXK];
    __shared__ float red_s[4];

    // ---------- load grid (int4), init labels ----------
    {
        const int4* gp = (const int4*)(grid + (size_t)b * HW);
        if (tid < 225) {
            int4 g = gp[tid];
            int i = tid * 4;
            color_s[i + 0] = g.x; lab_s[i + 0] = (g.x > 0) ? (i + 0) : SENTV;
            color_s[i + 1] = g.y; lab_s[i + 1] = (g.y > 0) ? (i + 1) : SENTV;
            color_s[i + 2] = g.z; lab_s[i + 2] = (g.z > 0) ? (i + 2) : SENTV;
            color_s[i + 3] = g.w; lab_s[i + 3] = (g.w > 0) ? (i + 3) : SENTV;
        }
    }
    __syncthreads();

    // ---------- CCL: min-label propagation + path compression ----------
    for (;;) {
        if (tid == 0) changed_s = 0;
        for (int i = tid; i < HW; i += 512) {   // sweep 1 (no check)
            int c = color_s[i];
            if (c <= 0) continue;
            int m = lab_s[i];
            int r = i / WWID;
            int cc = i - r * WWID;
            if (r > 0        && color_s[i - WWID] == c) m = min(m, lab_s[i - WWID]);
            if (r < HH - 1   && color_s[i + WWID] == c) m = min(m, lab_s[i + WWID]);
            if (cc > 0       && color_s[i - 1]    == c) m = min(m, lab_s[i - 1]);
            if (cc < WWID-1  && color_s[i + 1]    == c) m = min(m, lab_s[i + 1]);
            for (;;) { int p = lab_s[m]; if (p >= m) break; m = p; }
            if (m < lab_s[i]) lab_s[i] = m;
        }
        __syncthreads();
        for (int i = tid; i < HW; i += 512) {   // sweep 2 (with check)
            int c = color_s[i];
            if (c <= 0) continue;
            int m = lab_s[i];
            int r = i / WWID;
            int cc = i - r * WWID;
            if (r > 0        && color_s[i - WWID] == c) m = min(m, lab_s[i - WWID]);
            if (r < HH - 1   && color_s[i + WWID] == c) m = min(m, lab_s[i + WWID]);
            if (cc > 0       && color_s[i - 1]    == c) m = min(m, lab_s[i - 1]);
            if (cc < WWID-1  && color_s[i + 1]    == c) m = min(m, lab_s[i + 1]);
            for (;;) { int p = lab_s[m]; if (p >= m) break; m = p; }
            if (m < lab_s[i]) { lab_s[i] = m; changed_s = 1; }
        }
        __syncthreads();
        int ch = changed_s;
        __syncthreads();
        if (!ch) break;
    }

    // ---------- first 16 roots in raster order (wave 0 ballot scan) ----------
    if (tid < 64) {
        int base = 0;
        for (int chk = 0; chk < 15; ++chk) {
            int cell = chk * 64 + tid;
            bool isr = (cell < HW) && (color_s[cell] > 0) && (lab_s[cell] == cell);
            unsigned long long mask = __ballot(isr);
            int rank = base + __popcll(mask & ((1ull << tid) - 1ull));
            if (isr && rank < MAXK) root_s[rank] = cell;
            base += __popcll(mask);
        }
        if (tid == 0) nroot_s = base;
        if (tid < MAXK) { by0[tid] = HH; by1[tid] = -1; bx0[tid] = WWID; bx1[tid] = -1; }
    }
    __syncthreads();

    // ---------- bboxes via LDS atomics ----------
    const int nval = min(nroot_s, MAXK);
    for (int i = tid; i < HW; i += 512) {
        if (color_s[i] <= 0) continue;
        int L = lab_s[i];
        int s = -1;
        for (int k = 0; k < nval; ++k) if (root_s[k] == L) { s = k; break; }
        if (s >= 0) {
            int r = i / WWID;
            int cc = i - r * WWID;
            atomicMin(&by0[s], r); atomicMax(&by1[s], r);
            atomicMin(&bx0[s], cc); atomicMax(&bx1[s], cc);
        }
    }
    __syncthreads();

    // ---------- slot meta + structure-mean partial ----------
    if (tid < MAXK) {
        int v = (tid < nval) ? 1 : 0;
        sval[tid] = v;
        sval_ws[b * MAXK + tid] = v;
        if (v) {
            sy[tid] = by0[tid]; sx[tid] = bx0[tid];
            shh[tid] = by1[tid] + 1 - by0[tid];
            sww[tid] = bx1[tid] + 1 - bx0[tid];
            scol[tid] = color_s[root_s[tid]];
        } else { sy[tid] = 0; sx[tid] = 0; shh[tid] = 1; sww[tid] = 1; scol[tid] = 0; }
    }
    float s_mean = 0.f;
    if (tid < DD) {
        const float* sr = structure_rep + (size_t)b * KS * DD + tid;
        for (int j = 0; j < KS; ++j) s_mean += sr[(size_t)j * DD];
        s_mean *= (1.0f / (float)KS);
    }
    {
        float ss = s_mean * s_mean;
        #pragma unroll
        for (int off = 32; off > 0; off >>= 1) ss += __shfl_xor(ss, off);
        if (tx == 0 && wv < 4) red_s[wv] = ss;
    }
    __syncthreads();   // slot meta + red_s ready

    if (tid < DD) {
        float nrm = sqrtf(red_s[0] + red_s[1] + red_s[2] + red_s[3]);
        sn_ws[(size_t)b * DD + tid] = s_mean / fmaxf(nrm, 1e-8f);
    }

    // ---------- bbox pooling: wave wv pools slots wv and wv+8 ----------
    #pragma unroll
    for (int rr = 0; rr < 2; ++rr) {
        const int slot = rr * 8 + wv;
        float* crow = comb_ws + ((size_t)b * MAXK + slot) * A_LD;
        float4 pv = make_float4(0.f, 0.f, 0.f, 0.f);
        if (sval[slot]) {
            int y = sy[slot], x = sx[slot], h = shh[slot], w = sww[slot];
            float4 sum = make_float4(0.f, 0.f, 0.f, 0.f);
            for (int yy = y; yy < y + h; ++yy) {
                const float* p = grid_emb + ((size_t)(b * HH + yy) * WWID + x) * DD + c0;
                for (int xx = 0; xx < w; ++xx) {
                    float4 v = *(const float4*)(p + (size_t)xx * DD);
                    sum.x += v.x; sum.y += v.y; sum.z += v.z; sum.w += v.w;
                }
            }
            float inv = 1.0f / (float)(h * w);
            pv.x = sum.x * inv; pv.y = sum.y * inv; pv.z = sum.z * inv; pv.w = sum.w * inv;
        }
        *(float4*)(crow + c0) = pv;
        if (tx < 8) {
            float f = 0.f;
            if (tx < 5 && sval[slot]) {
                switch (tx) {
                    case 0: f = (float)scol[slot] / 9.0f;  break;
                    case 1: f = (float)sx[slot]  / 30.0f;  break;
                    case 2: f = (float)sy[slot]  / 30.0f;  break;
                    case 3: f = (float)sww[slot] / 30.0f;  break;
                    case 4: f = (float)shh[slot] / 30.0f;  break;
                }
            }
            crow[256 + tx] = f;   // feats 256..260, pads 261..263 = 0
        }
    }
}

// ======================= K2: MLP (3 pipelined split-K GEMMs) =================
__global__ __launch_bounds__(512, 2) void ccce_mlp(
    const float* __restrict__ comb_ws,
    const float* __restrict__ sn_ws,
    const int* __restrict__ sval_ws,
    const float* __restrict__ W1, const float* __restrict__ b1,
    const float* __restrict__ W2, const float* __restrict__ b2,
    const float* __restrict__ Wp, const float* __restrict__ bp,
    const float* __restrict__ gvec, const float* __restrict__ bvec,
    const float* __restrict__ ortho_scale,
    float* __restrict__ out)
{
    const int b   = blockIdx.x >> 1;
    const int h8  = blockIdx.x & 1;
    const int tid = threadIdx.x;
    const int tx  = tid & 63;
    const int wv  = tid >> 6;
    const int c0  = tx * 4;

    __shared__ __align__(16) float A1_s[8][A_LD];
    __shared__ __align__(16) float A2_s[8][A_LD];
    __shared__ __align__(16) float part_s[4][8][DD];
    __shared__ __align__(16) float sn_s[DD];
    __shared__ int sval_sh[8];

    // ---------- load A (8 rows of comb), sn, sval ----------
    {
        const float4* src = (const float4*)(comb_ws + ((size_t)b * MAXK + h8 * 8) * A_LD);
        float4* dst = (float4*)A1_s;
        for (int i = tid; i < 8 * (A_LD / 4); i += 512) dst[i] = src[i];
        if (tid < DD / 4) ((float4*)sn_s)[tid] = ((const float4*)(sn_ws + (size_t)b * DD))[tid];
        if (tid < 8) sval_sh[tid] = sval_ws[b * MAXK + h8 * 8 + tid];
    }
    __syncthreads();

    // ================= GEMM1: hdn = gelu(comb @ W1 + b1) =================
    gemm_phase(A1_s, W1, part_s, wv, c0);
    {
        float4 s = *(const float4*)(&part_s[0][wv][c0]);
        #pragma unroll
        for (int w = 1; w < 4; ++w) {
            float4 p = *(const float4*)(&part_s[w][wv][c0]);
            s.x += p.x; s.y += p.y; s.z += p.z; s.w += p.w;
        }
        #pragma unroll
        for (int j = 0; j < 5; ++j) {   // bbox-feature k's 256..260
            float a = A1_s[wv][256 + j];
            float4 wrow = *(const float4*)(W1 + (size_t)(256 + j) * DD + c0);
            s.x += a * wrow.x; s.y += a * wrow.y; s.z += a * wrow.z; s.w += a * wrow.w;
        }
        float4 bb = *(const float4*)(b1 + c0);
        float4 hv;
        hv.x = gelu_exact(s.x + bb.x);
        hv.y = gelu_exact(s.y + bb.y);
        hv.z = gelu_exact(s.z + bb.z);
        hv.w = gelu_exact(s.w + bb.w);
        *(float4*)(&A2_s[wv][c0]) = hv;
    }
    __syncthreads();

    // ================= GEMM2: obj = (hdn @ W2 + b2) * valid; ortho ========
    gemm_phase(A2_s, W2, part_s, wv, c0);
    {
        float4 s = *(const float4*)(&part_s[0][wv][c0]);
        #pragma unroll
        for (int w = 1; w < 4; ++w) {
            float4 p = *(const float4*)(&part_s[w][wv][c0]);
            s.x += p.x; s.y += p.y; s.z += p.z; s.w += p.w;
        }
        float4 bb = *(const float4*)(b2 + c0);
        float vm = sval_sh[wv] ? 1.f : 0.f;
        float o0 = (s.x + bb.x) * vm;
        float o1 = (s.y + bb.y) * vm;
        float o2 = (s.z + bb.z) * vm;
        float o3 = (s.w + bb.w) * vm;
        float4 snv = *(const float4*)(sn_s + c0);
        float p = o0 * snv.x + o1 * snv.y + o2 * snv.z + o3 * snv.w;
        #pragma unroll
        for (int off = 32; off > 0; off >>= 1) p += __shfl_xor(p, off);
        float osc = ortho_scale[0];
        float4 co;
        co.x = (o0 - p * snv.x) * osc;
        co.y = (o1 - p * snv.y) * osc;
        co.z = (o2 - p * snv.z) * osc;
        co.w = (o3 - p * snv.w) * osc;
        *(float4*)(&A1_s[wv][c0]) = co;
    }
    __syncthreads();

    // ================= GEMM3: co @ Wp + bp, LayerNorm =====================
    gemm_phase(A1_s, Wp, part_s, wv, c0);
    {
        float4 s = *(const float4*)(&part_s[0][wv][c0]);
        #pragma unroll
        for (int w = 1; w < 4; ++w) {
            float4 p = *(const float4*)(&part_s[w][wv][c0]);
            s.x += p.x; s.y += p.y; s.z += p.z; s.w += p.w;
        }
        float4 bb = *(const float4*)(bp + c0);
        float v0 = s.x + bb.x;
        float v1 = s.y + bb.y;
        float v2 = s.z + bb.z;
        float v3 = s.w + bb.w;
        float sm = v0 + v1 + v2 + v3;
        float sq = v0 * v0 + v1 * v1 + v2 * v2 + v3 * v3;
        #pragma unroll
        for (int off = 32; off > 0; off >>= 1) {
            sm += __shfl_xor(sm, off);
            sq += __shfl_xor(sq, off);
        }
        float mu   = sm * (1.0f / 256.0f);
        float var  = fmaxf(sq * (1.0f / 256.0f) - mu * mu, 0.0f);
        float rstd = 1.0f / sqrtf(var + 1e-5f);
        float4 gv = *(const float4*)(gvec + c0);
        float4 bv = *(const float4*)(bvec + c0);
        float4 o;
        o.x = (v0 - mu) * rstd * gv.x + bv.x;
        o.y = (v1 - mu) * rstd * gv.y + bv.y;
        o.z = (v2 - mu) * rstd * gv.z + bv.z;
        o.w = (v3 - mu) * rstd * gv.w + bv.w;
        *(float4*)(out + ((size_t)b * MAXK + h8 * 8 + wv) * DD + c0) = o;
    }
}

// ================= Fallback: round-4 fused kernel (ws too small) =============
__global__ __launch_bounds__(512, 2) void ccce_fused(
    const float* __restrict__ grid_emb,
    const int* __restrict__ grid,
    const float* __restrict__ structure_rep,
    const float* __restrict__ W1, const float* __restrict__ b1,
    const float* __restrict__ W2, const float* __restrict__ b2,
    const float* __restrict__ Wp, const float* __restrict__ bp,
    const float* __restrict__ gvec, const float* __restrict__ bvec,
    const float* __restrict__ ortho_scale,
    float* __restrict__ out, int KS)
{
    const int b   = blockIdx.x >> 1;
    const int h8  = blockIdx.x & 1;
    const int tid = threadIdx.x;
    const int tx  = tid & 63;
    const int wv  = tid >> 6;
    const int c0  = tx * 4;

    __shared__ int color_s[HW];
    __shared__ int lab_s[HW];
    __shared__ int changed_s;
    __shared__ int root_s[MAXK];
    __shared__ int nroot_s;
    __shared__ int by0[MAXK], by1[MAXK], bx0[MAXK], bx1[MAXK];
    __shared__ int sy[MAXK], sx[MAXK], shh[MAXK], sww[MAXK], scol[MAXK], sval[MAXK];
    __shared__ __align__(16) float A1_s[8][A_LD];
    __shared__ __align__(16) float A2_s[8][A_LD];
    __shared__ __align__(16) float part_s[4][8][DD];
    __shared__ __align__(16) float sn_s[DD];
    __shared__ float red_s[4];

    {
        const int4* gp = (const int4*)(grid + (size_t)b * HW);
        if (tid < 225) {
            int4 g = gp[tid];
            int i = tid * 4;
            color_s[i + 0] = g.x; lab_s[i + 0] = (g.x > 0) ? (i + 0) : SENTV;
            color_s[i + 1] = g.y; lab_s[i + 1] = (g.y > 0) ? (i + 1) : SENTV;
            color_s[i + 2] = g.z; lab_s[i + 2] = (g.z > 0) ? (i + 2) : SENTV;
            color_s[i + 3] = g.w; lab_s[i + 3] = (g.w > 0) ? (i + 3) : SENTV;
        }
    }
    __syncthreads();

    for (;;) {
        if (tid == 0) changed_s = 0;
        for (int i = tid; i < HW; i += 512) {
            int c = color_s[i];
            if (c <= 0) continue;
            int m = lab_s[i];
            int r = i / WWID;
            int cc = i - r * WWID;
            if (r > 0        && color_s[i - WWID] == c) m = min(m, lab_s[i - WWID]);
            if (r < HH - 1   && color_s[i + WWID] == c) m = min(m, lab_s[i + WWID]);
            if (cc > 0       && color_s[i - 1]    == c) m = min(m, lab_s[i - 1]);
            if (cc < WWID-1  && color_s[i + 1]    == c) m = min(m, lab_s[i + 1]);
            for (;;) { int p = lab_s[m]; if (p >= m) break; m = p; }
            if (m < lab_s[i]) lab_s[i] = m;
        }
        __syncthreads();
        for (int i = tid; i < HW; i += 512) {
            int c = color_s[i];
            if (c <= 0) continue;
            int m = lab_s[i];
            int r = i / WWID;
            int cc = i - r * WWID;
            if (r > 0        && color_s[i - WWID] == c) m = min(m, lab_s[i - WWID]);
            if (r < HH - 1   && color_s[i + WWID] == c) m = min(m, lab_s[i + WWID]);
            if (cc > 0       && color_s[i - 1]    == c) m = min(m, lab_s[i - 1]);
            if (cc < WWID-1  && color_s[i + 1]    == c) m = min(m, lab_s[i + 1]);
            for (;;) { int p = lab_s[m]; if (p >= m) break; m = p; }
            if (m < lab_s[i]) { lab_s[i] = m; changed_s = 1; }
        }
        __syncthreads();
        int ch = changed_s;
        __syncthreads();
        if (!ch) break;
    }

    if (tid < 64) {
        int base = 0;
        for (int chk = 0; chk < 15; ++chk) {
            int cell = chk * 64 + tid;
            bool isr = (cell < HW) && (color_s[cell] > 0) && (lab_s[cell] == cell);
            unsigned long long mask = __ballot(isr);
            int rank = base + __popcll(mask & ((1ull << tid) - 1ull));
            if (isr && rank < MAXK) root_s[rank] = cell;
            base += __popcll(mask);
        }
        if (tid == 0) nroot_s = base;
        if (tid < MAXK) { by0[tid] = HH; by1[tid] = -1; bx0[tid] = WWID; bx1[tid] = -1; }
    }
    __syncthreads();

    const int nval = min(nroot_s, MAXK);
    for (int i = tid; i < HW; i += 512) {
        if (color_s[i] <= 0) continue;
        int L = lab_s[i];
        int s = -1;
        for (int k = 0; k < nval; ++k) if (root_s[k] == L) { s = k; break; }
        if (s >= 0) {
            int r = i / WWID;
            int cc = i - r * WWID;
            atomicMin(&by0[s], r); atomicMax(&by1[s], r);
            atomicMin(&bx0[s], cc); atomicMax(&bx1[s], cc);
        }
    }
    __syncthreads();

    if (tid < MAXK) {
        int v = (tid < nval) ? 1 : 0;
        sval[tid] = v;
        if (v) {
            sy[tid] = by0[tid]; sx[tid] = bx0[tid];
            shh[tid] = by1[tid] + 1 - by0[tid];
            sww[tid] = bx1[tid] + 1 - bx0[tid];
            scol[tid] = color_s[root_s[tid]];
        } else { sy[tid] = 0; sx[tid] = 0; shh[tid] = 1; sww[tid] = 1; scol[tid] = 0; }
    }
    float s_mean = 0.f;
    if (tid < DD) {
        const float* sr = structure_rep + (size_t)b * KS * DD + tid;
        for (int j = 0; j < KS; ++j) s_mean += sr[(size_t)j * DD];
        s_mean *= (1.0f / (float)KS);
    }
    {
        float ss = s_mean * s_mean;
        #pragma unroll
        for (int off = 32; off > 0; off >>= 1) ss += __shfl_xor(ss, off);
        if (tx == 0 && wv < 4) red_s[wv] = ss;
    }
    __syncthreads();

    if (tid < DD) {
        float nrm = sqrtf(red_s[0] + red_s[1] + red_s[2] + red_s[3]);
        sn_s[tid] = s_mean / fmaxf(nrm, 1e-8f);
    }
    {
        const int slot = h8 * 8 + wv;
        float4 pv = make_float4(0.f, 0.f, 0.f, 0.f);
        if (sval[slot]) {
            int y = sy[slot], x = sx[slot], h = shh[slot], w = sww[slot];
            float4 sum = make_float4(0.f, 0.f, 0.f, 0.f);
            for (int yy = y; yy < y + h; ++yy) {
                const float* p = grid_emb + ((size_t)(b * HH + yy) * WWID + x) * DD + c0;
                for (int xx = 0; xx < w; ++xx) {
                    float4 v = *(const float4*)(p + (size_t)xx * DD);
                    sum.x += v.x; sum.y += v.y; sum.z += v.z; sum.w += v.w;
                }
            }
            float inv = 1.0f / (float)(h * w);
            pv.x = sum.x * inv; pv.y = sum.y * inv; pv.z = sum.z * inv; pv.w = sum.w * inv;
        }
        *(float4*)(&A1_s[wv][c0]) = pv;
        if (tx < 5) {
            float f = 0.f;
            if (sval[slot]) {
                switch (tx) {
                    case 0: f = (float)scol[slot] / 9.0f;  break;
                    case 1: f = (float)sx[slot]  / 30.0f;  break;
                    case 2: f = (float)sy[slot]  / 30.0f;  break;
                    case 3: f = (float)sww[slot] / 30.0f;  break;
                    case 4: f = (float)shh[slot] / 30.0f;  break;
                }
            }
            A1_s[wv][256 + tx] = f;
        }
    }
    __syncthreads();

    gemm_phase(A1_s, W1, part_s, wv, c0);
    {
        float4 s = *(const float4*)(&part_s[0][wv][c0]);
        #pragma unroll
        for (int w = 1; w < 4; ++w) {
            float4 p = *(const float4*)(&part_s[w][wv][c0]);
            s.x += p.x; s.y += p.y; s.z += p.z; s.w += p.w;
        }
        #pragma unroll
        for (int j = 0; j < 5; ++j) {
            float a = A1_s[wv][256 + j];
            float4 wrow = *(const float4*)(W1 + (size_t)(256 + j) * DD + c0);
            s.x += a * wrow.x; s.y += a * wrow.y; s.z += a * wrow.z; s.w += a * wrow.w;
        }
        float4 bb = *(const float4*)(b1 + c0);
        float4 hv;
        hv.x = gelu_exact(s.x + bb.x);
        hv.y = gelu_exact(s.y + bb.y);
        hv.z = gelu_exact(s.z + bb.z);
        hv.w = gelu_exact(s.w + bb.w);
        *(float4*)(&A2_s[wv][c0]) = hv;
    }
    __syncthreads();

    gemm_phase(A2_s, W2, part_s, wv, c0);
    {
        float4 s = *(const float4*)(&part_s[0][wv][c0]);
        #pragma unroll
        for (int w = 1; w < 4; ++w) {
            float4 p = *(const float4*)(&part_s[w][wv][c0]);
            s.x += p.x; s.y += p.y; s.z += p.z; s.w += p.w;
        }
        float4 bb = *(const float4*)(b2 + c0);
        float vm = sval[h8 * 8 + wv] ? 1.f : 0.f;
        float o0 = (s.x + bb.x) * vm;
        float o1 = (s.y + bb.y) * vm;
        float o2 = (s.z + bb.z) * vm;
        float o3 = (s.w + bb.w) * vm;
        float4 snv = *(const float4*)(sn_s + c0);
        float p = o0 * snv.x + o1 * snv.y + o2 * snv.z + o3 * snv.w;
        #pragma unroll
        for (int off = 32; off > 0; off >>= 1) p += __shfl_xor(p, off);
        float osc = ortho_scale[0];
        float4 co;
        co.x = (o0 - p * snv.x) * osc;
        co.y = (o1 - p * snv.y) * osc;
        co.z = (o2 - p * snv.z) * osc;
        co.w = (o3 - p * snv.w) * osc;
        *(float4*)(&A1_s[wv][c0]) = co;
    }
    __syncthreads();

    gemm_phase(A1_s, Wp, part_s, wv, c0);
    {
        float4 s = *(const float4*)(&part_s[0][wv][c0]);
        #pragma unroll
        for (int w = 1; w < 4; ++w) {
            float4 p = *(const float4*)(&part_s[w][wv][c0]);
            s.x += p.x; s.y += p.y; s.z += p.z; s.w += p.w;
        }
        float4 bb = *(const float4*)(bp + c0);
        float v0 = s.x + bb.x;
        float v1 = s.y + bb.y;
        float v2 = s.z + bb.z;
        float v3 = s.w + bb.w;
        float sm = v0 + v1 + v2 + v3;
        float sq = v0 * v0 + v1 * v1 + v2 * v2 + v3 * v3;
        #pragma unroll
        for (int off = 32; off > 0; off >>= 1) {
            sm += __shfl_xor(sm, off);
            sq += __shfl_xor(sq, off);
        }
        float mu   = sm * (1.0f / 256.0f);
        float var  = fmaxf(sq * (1.0f / 256.0f) - mu * mu, 0.0f);
        float rstd = 1.0f / sqrtf(var + 1e-5f);
        float4 gv = *(const float4*)(gvec + c0);
        float4 bv = *(const float4*)(bvec + c0);
        float4 o;
        o.x = (v0 - mu) * rstd * gv.x + bv.x;
        o.y = (v1 - mu) * rstd * gv.y + bv.y;
        o.z = (v2 - mu) * rstd * gv.z + bv.z;
        o.w = (v3 - mu) * rstd * gv.w + bv.w;
        *(float4*)(out + ((size_t)b * MAXK + h8 * 8 + wv) * DD + c0) = o;
    }
}

extern "C" void kernel_launch(void* const* d_in, const int* in_sizes, int n_in,
                              void* d_out, int out_size, void* d_ws, size_t ws_size,
                              hipStream_t stream) {
    const float* grid_emb = (const float*)d_in[0];
    const int*   grid     = (const int*)d_in[1];
    const float* srep     = (const float*)d_in[2];
    const float* W1v = (const float*)d_in[3];
    const float* b1v = (const float*)d_in[4];
    const float* W2v = (const float*)d_in[5];
    const float* b2v = (const float*)d_in[6];
    const float* Wpv = (const float*)d_in[7];
    const float* bpv = (const float*)d_in[8];
    const float* gv  = (const float*)d_in[9];
    const float* bv  = (const float*)d_in[10];
    const float* osv = (const float*)d_in[11];
    float* out = (float*)d_out;

    const int B  = in_sizes[1] / HW;
    const int KS = in_sizes[2] / (B * DD);

    const size_t comb_f = (size_t)B * MAXK * A_LD;
    const size_t sn_f   = (size_t)B * DD;
    const size_t need   = (comb_f + sn_f) * sizeof(float) + (size_t)B * MAXK * sizeof(int);

    if (ws_size >= need) {
        float* comb_ws = (float*)d_ws;
        float* sn_ws   = comb_ws + comb_f;
        int*   sval_ws = (int*)(sn_ws + sn_f);
        hipLaunchKernelGGL(ccce_prep, dim3(B), dim3(512), 0, stream,
                           grid_emb, grid, srep, comb_ws, sn_ws, sval_ws, KS);
        hipLaunchKernelGGL(ccce_mlp, dim3(B * 2), dim3(512), 0, stream,
                           comb_ws, sn_ws, sval_ws, W1v, b1v, W2v, b2v, Wpv, bpv,
                           gv, bv, osv, out);
    } else {
        hipLaunchKernelGGL(ccce_fused, dim3(B * 2), dim3(512), 0, stream,
                           grid_emb, grid, srep, W1v, b1v, W2v, b2v, Wpv, bpv,
                           gv, bv, osv, out, KS);
    }
}

// Round 6
// 28.899 us; speedup vs baseline: 1.2498x; 1.2498x over previous
//
#include <hip/hip_runtime.h>
#include <math.h>

#define HH 30
#define WWID 30
#define HW 900
#define SENTV 900
#define DD 256
#define MAXK 16
#define A_LD 264

#define COMP(v, jj) ((jj) == 0 ? (v).x : (jj) == 1 ? (v).y : (jj) == 2 ? (v).z : (v).w)

__device__ __forceinline__ float gelu_exact(float x) {
    return 0.5f * x * (1.0f + erff(x * 0.70710678118654752440f));
}

// Split-K GEMM phase: wave wv owns k in [32wv, 32wv+32), 8 rows x 4 cols/thread.
// Software-pipelined: chunk c+1's 8 weight float4s issued before chunk c's FMAs.
__device__ __forceinline__ void gemm_phase(
    const float (* __restrict__ Asrc)[A_LD],
    const float* __restrict__ Wm,
    float (* __restrict__ part)[8][DD],
    int wv, int c0)
{
    const int kbase = wv * 32;
    float acc[8][4];
    #pragma unroll
    for (int r = 0; r < 8; ++r) { acc[r][0] = 0.f; acc[r][1] = 0.f; acc[r][2] = 0.f; acc[r][3] = 0.f; }

    const float* wp = Wm + (size_t)kbase * DD + c0;
    float4 wc[8], wn[8];
    #pragma unroll
    for (int j = 0; j < 8; ++j) wc[j] = *(const float4*)(wp + (size_t)j * DD);

    #pragma unroll
    for (int ch = 0; ch < 4; ++ch) {
        if (ch < 3) {   // prefetch next weight chunk
            const float* wpn = wp + (size_t)((ch + 1) * 8) * DD;
            #pragma unroll
            for (int j = 0; j < 8; ++j) wn[j] = *(const float4*)(wpn + (size_t)j * DD);
        }
        float4 aA[8], aB[8];
        #pragma unroll
        for (int r = 0; r < 8; ++r) {
            aA[r] = *(const float4*)(&Asrc[r][kbase + ch * 8]);
            aB[r] = *(const float4*)(&Asrc[r][kbase + ch * 8 + 4]);
        }
        #pragma unroll
        for (int j = 0; j < 4; ++j) {
            #pragma unroll
            for (int r = 0; r < 8; ++r) {
                float av = COMP(aA[r], j);
                acc[r][0] += av * wc[j].x;
                acc[r][1] += av * wc[j].y;
                acc[r][2] += av * wc[j].z;
                acc[r][3] += av * wc[j].w;
            }
        }
        #pragma unroll
        for (int j = 0; j < 4; ++j) {
            #pragma unroll
            for (int r = 0; r < 8; ++r) {
                float av = COMP(aB[r], j);
                acc[r][0] += av * wc[4 + j].x;
                acc[r][1] += av * wc[4 + j].y;
                acc[r][2] += av * wc[4 + j].z;
                acc[r][3] += av * wc[4 + j].w;
            }
        }
        if (ch < 3) {
            #pragma unroll
            for (int j = 0; j < 8; ++j) wc[j] = wn[j];
        }
    }

    if (wv < 4) {
        #pragma unroll
        for (int r = 0; r < 8; ++r)
            *(float4*)(&part[wv][r][c0]) = make_float4(acc[r][0], acc[r][1], acc[r][2], acc[r][3]);
    }
    __syncthreads();
    if (wv >= 4) {
        #pragma unroll
        for (int r = 0; r < 8; ++r) {
            float4 p = *(const float4*)(&part[wv - 4][r][c0]);
            p.x += acc[r][0]; p.y += acc[r][1]; p.z += acc[r][2]; p.w += acc[r][3];
            *(float4*)(&part[wv - 4][r][c0]) = p;
        }
    }
    __syncthreads();
}

__global__ __launch_bounds__(512, 2) void ccce_fused(
    const float* __restrict__ grid_emb,
    const int* __restrict__ grid,
    const float* __restrict__ structure_rep,
    const float* __restrict__ W1, const float* __restrict__ b1,
    const float* __restrict__ W2, const float* __restrict__ b2,
    const float* __restrict__ Wp, const float* __restrict__ bp,
    const float* __restrict__ gvec, const float* __restrict__ bvec,
    const float* __restrict__ ortho_scale,
    float* __restrict__ out, int KS)
{
    const int b   = blockIdx.x >> 1;
    const int h8  = blockIdx.x & 1;
    const int tid = threadIdx.x;
    const int tx  = tid & 63;
    const int wv  = tid >> 6;
    const int c0  = tx * 4;

    __shared__ int color_s[HW];
    __shared__ int lab_s[HW];
    __shared__ int slot_of[HW];
    __shared__ int root_s[MAXK];
    __shared__ int nroot_s;
    __shared__ int by0[MAXK], by1[MAXK], bx0[MAXK], bx1[MAXK];
    __shared__ __align__(16) float A1_s[8][A_LD];
    __shared__ __align__(16) float A2_s[8][A_LD];
    __shared__ __align__(16) float part_s[4][8][DD];
    __shared__ __align__(16) float sn_s[DD];
    __shared__ float red_s[4];

    // ---------- issue long-latency loads first ----------
    const int4* gp = (const int4*)(grid + (size_t)b * HW);
    int4 g;
    if (tid < 225) g = gp[tid];

    // structure_rep loads issued now; summed AFTER bbox (latency hides under CCL)
    const bool do_s = (tid < DD);
    float sl0 = 0.f, sl1 = 0.f, sl2 = 0.f, sl3 = 0.f, sl4 = 0.f, sl5 = 0.f, sl6 = 0.f, sl7 = 0.f;
    float s_gen = 0.f;
    {
        const float* sr = structure_rep + (size_t)b * KS * DD + tid;
        if (do_s) {
            if (KS == 8) {
                sl0 = sr[0 * DD]; sl1 = sr[1 * DD]; sl2 = sr[2 * DD]; sl3 = sr[3 * DD];
                sl4 = sr[4 * DD]; sl5 = sr[5 * DD]; sl6 = sr[6 * DD]; sl7 = sr[7 * DD];
            } else {
                for (int j = 0; j < KS; ++j) s_gen += sr[(size_t)j * DD];
            }
        }
    }

    // ---------- grid -> LDS, init labels ----------
    if (tid < 225) {
        int i = tid * 4;
        color_s[i + 0] = g.x; lab_s[i + 0] = (g.x > 0) ? (i + 0) : SENTV;
        color_s[i + 1] = g.y; lab_s[i + 1] = (g.y > 0) ? (i + 1) : SENTV;
        color_s[i + 2] = g.z; lab_s[i + 2] = (g.z > 0) ? (i + 2) : SENTV;
        color_s[i + 3] = g.w; lab_s[i + 3] = (g.w > 0) ? (i + 3) : SENTV;
    }
    __syncthreads();

    // ---------- cache per-cell neighbor-same-color masks (2 cells/thread) ----
    const int li0 = tid;
    const int li1 = tid + 512;
    int nm0 = 0, nm1 = 0;
    {
        int c = color_s[li0];
        if (c > 0) {
            int r = li0 / WWID, cc = li0 - (li0 / WWID) * WWID;
            nm0 = 16;
            if (r > 0        && color_s[li0 - WWID] == c) nm0 |= 1;
            if (r < HH - 1   && color_s[li0 + WWID] == c) nm0 |= 2;
            if (cc > 0       && color_s[li0 - 1]    == c) nm0 |= 4;
            if (cc < WWID-1  && color_s[li0 + 1]    == c) nm0 |= 8;
        }
    }
    if (li1 < HW) {
        int c = color_s[li1];
        if (c > 0) {
            int r = li1 / WWID, cc = li1 - (li1 / WWID) * WWID;
            nm1 = 16;
            if (r > 0        && color_s[li1 - WWID] == c) nm1 |= 1;
            if (r < HH - 1   && color_s[li1 + WWID] == c) nm1 |= 2;
            if (cc > 0       && color_s[li1 - 1]    == c) nm1 |= 4;
            if (cc < WWID-1  && color_s[li1 + 1]    == c) nm1 |= 8;
        }
    }

    // ---------- CCL: min-label relaxation, 1 barrier per sweep ----------
    // Monotone-decreasing labels; fixpoint = min linear index per component,
    // identical to the reference's nbr_min + pointer-jump loop fixpoint.
    for (;;) {
        int ch = 0;
        int m0 = 0, m1 = 0;
        if (nm0 & 16) {
            m0 = lab_s[li0];
            if (nm0 & 1) m0 = min(m0, lab_s[li0 - WWID]);
            if (nm0 & 2) m0 = min(m0, lab_s[li0 + WWID]);
            if (nm0 & 4) m0 = min(m0, lab_s[li0 - 1]);
            if (nm0 & 8) m0 = min(m0, lab_s[li0 + 1]);
        }
        if (nm1 & 16) {
            m1 = lab_s[li1];
            if (nm1 & 1) m1 = min(m1, lab_s[li1 - WWID]);
            if (nm1 & 2) m1 = min(m1, lab_s[li1 + WWID]);
            if (nm1 & 4) m1 = min(m1, lab_s[li1 - 1]);
            if (nm1 & 8) m1 = min(m1, lab_s[li1 + 1]);
        }
        // two bounded path-compression jumps (interleaved, independent chains)
        if (nm0 & 16) m0 = min(m0, lab_s[m0]);
        if (nm1 & 16) m1 = min(m1, lab_s[m1]);
        if (nm0 & 16) m0 = min(m0, lab_s[m0]);
        if (nm1 & 16) m1 = min(m1, lab_s[m1]);
        if ((nm0 & 16) && m0 < lab_s[li0]) { lab_s[li0] = m0; ch = 1; }
        if ((nm1 & 16) && m1 < lab_s[li1]) { lab_s[li1] = m1; ch = 1; }
        if (__syncthreads_count(ch) == 0) break;
    }

    // ---------- roots (wave 0) || slot_of init (waves 1-7) ----------
    if (tid < 64) {
        int base = 0;
        for (int chk = 0; chk < 15; ++chk) {
            int cell = chk * 64 + tid;
            bool isr = (cell < HW) && (color_s[cell] > 0) && (lab_s[cell] == cell);
            unsigned long long mask = __ballot(isr);
            int rank = base + __popcll(mask & ((1ull << tid) - 1ull));
            if (isr && rank < MAXK) root_s[rank] = cell;
            base += __popcll(mask);
        }
        if (tid == 0) nroot_s = base;
    } else {
        for (int i = tid - 64; i < HW; i += 448) slot_of[i] = -1;
        if (tid >= 448 && tid < 448 + MAXK) {
            int k = tid - 448;
            by0[k] = HH; by1[k] = -1; bx0[k] = WWID; bx1[k] = -1;
        }
    }
    __syncthreads();

    const int nval = min(nroot_s, MAXK);
    if (tid < nval) slot_of[root_s[tid]] = tid;
    __syncthreads();

    // ---------- bbox pass: one slot_of lookup per fg cell ----------
    if (nm0 & 16) {
        int s = slot_of[lab_s[li0]];
        if (s >= 0) {
            int r = li0 / WWID, cc = li0 - (li0 / WWID) * WWID;
            atomicMin(&by0[s], r); atomicMax(&by1[s], r);
            atomicMin(&bx0[s], cc); atomicMax(&bx1[s], cc);
        }
    }
    if (nm1 & 16) {
        int s = slot_of[lab_s[li1]];
        if (s >= 0) {
            int r = li1 / WWID, cc = li1 - (li1 / WWID) * WWID;
            atomicMin(&by0[s], r); atomicMax(&by1[s], r);
            atomicMin(&bx0[s], cc); atomicMax(&bx1[s], cc);
        }
    }

    // ---------- structure mean reduce (loads issued at kernel start) ----------
    float s_mean = (KS == 8)
        ? (sl0 + sl1 + sl2 + sl3 + sl4 + sl5 + sl6 + sl7) * 0.125f
        : s_gen * (1.0f / (float)KS);
    {
        float ss = s_mean * s_mean;
        #pragma unroll
        for (int off = 32; off > 0; off >>= 1) ss += __shfl_xor(ss, off);
        if (tx == 0 && wv < 4) red_s[wv] = ss;
    }
    __syncthreads();   // bboxes + red_s final

    // ---------- sn + per-wave slot meta + pooling ----------
    if (do_s) {
        float nrm = sqrtf(red_s[0] + red_s[1] + red_s[2] + red_s[3]);
        sn_s[tid] = s_mean / fmaxf(nrm, 1e-8f);
    }
    const int slot = h8 * 8 + wv;
    const int v_ok = (slot < nval) ? 1 : 0;   // wave-uniform; kept in reg for GEMM2 mask
    {
        float4 pv = make_float4(0.f, 0.f, 0.f, 0.f);
        int y = 0, x = 0, h = 1, w = 1, col = 0;
        if (v_ok) {
            y = by0[slot]; x = bx0[slot];
            h = by1[slot] + 1 - y; w = bx1[slot] + 1 - x;
            col = color_s[root_s[slot]];
            float4 sum = make_float4(0.f, 0.f, 0.f, 0.f);
            for (int yy = y; yy < y + h; ++yy) {
                const float* p = grid_emb + ((size_t)(b * HH + yy) * WWID + x) * DD + c0;
                for (int xx = 0; xx < w; ++xx) {
                    float4 vv = *(const float4*)(p + (size_t)xx * DD);
                    sum.x += vv.x; sum.y += vv.y; sum.z += vv.z; sum.w += vv.w;
                }
            }
            float inv = 1.0f / (float)(h * w);
            pv.x = sum.x * inv; pv.y = sum.y * inv; pv.z = sum.z * inv; pv.w = sum.w * inv;
        }
        *(float4*)(&A1_s[wv][c0]) = pv;
        if (tx < 8) {
            float f = 0.f;
            if (v_ok && tx < 5) {
                switch (tx) {
                    case 0: f = (float)col / 9.0f; break;
                    case 1: f = (float)x  / 30.0f; break;
                    case 2: f = (float)y  / 30.0f; break;
                    case 3: f = (float)w  / 30.0f; break;
                    case 4: f = (float)h  / 30.0f; break;
                }
            }
            A1_s[wv][256 + tx] = f;
        }
    }
    __syncthreads();   // A1 (comb) + sn ready

    // ================= GEMM1: hdn = gelu(comb @ W1 + b1) =================
    gemm_phase(A1_s, W1, part_s, wv, c0);
    {
        float4 s = *(const float4*)(&part_s[0][wv][c0]);
        #pragma unroll
        for (int w = 1; w < 4; ++w) {
            float4 p = *(const float4*)(&part_s[w][wv][c0]);
            s.x += p.x; s.y += p.y; s.z += p.z; s.w += p.w;
        }
        #pragma unroll
        for (int j = 0; j < 5; ++j) {   // bbox-feature k's 256..260
            float a = A1_s[wv][256 + j];
            float4 wrow = *(const float4*)(W1 + (size_t)(256 + j) * DD + c0);
            s.x += a * wrow.x; s.y += a * wrow.y; s.z += a * wrow.z; s.w += a * wrow.w;
        }
        float4 bb = *(const float4*)(b1 + c0);
        float4 hv;
        hv.x = gelu_exact(s.x + bb.x);
        hv.y = gelu_exact(s.y + bb.y);
        hv.z = gelu_exact(s.z + bb.z);
        hv.w = gelu_exact(s.w + bb.w);
        *(float4*)(&A2_s[wv][c0]) = hv;
    }
    __syncthreads();

    // ================= GEMM2: obj = (hdn @ W2 + b2) * valid; ortho ========
    gemm_phase(A2_s, W2, part_s, wv, c0);
    {
        float4 s = *(const float4*)(&part_s[0][wv][c0]);
        #pragma unroll
        for (int w = 1; w < 4; ++w) {
            float4 p = *(const float4*)(&part_s[w][wv][c0]);
            s.x += p.x; s.y += p.y; s.z += p.z; s.w += p.w;
        }
        float4 bb = *(const float4*)(b2 + c0);
        float vm = v_ok ? 1.f : 0.f;
        float o0 = (s.x + bb.x) * vm;
        float o1 = (s.y + bb.y) * vm;
        float o2 = (s.z + bb.z) * vm;
        float o3 = (s.w + bb.w) * vm;
        float4 snv = *(const float4*)(sn_s + c0);
        float p = o0 * snv.x + o1 * snv.y + o2 * snv.z + o3 * snv.w;
        #pragma unroll
        for (int off = 32; off > 0; off >>= 1) p += __shfl_xor(p, off);
        float osc = ortho_scale[0];
        float4 co;
        co.x = (o0 - p * snv.x) * osc;
        co.y = (o1 - p * snv.y) * osc;
        co.z = (o2 - p * snv.z) * osc;
        co.w = (o3 - p * snv.w) * osc;
        *(float4*)(&A1_s[wv][c0]) = co;
    }
    __syncthreads();

    // ================= GEMM3: co @ Wp + bp, LayerNorm =====================
    gemm_phase(A1_s, Wp, part_s, wv, c0);
    {
        float4 s = *(const float4*)(&part_s[0][wv][c0]);
        #pragma unroll
        for (int w = 1; w < 4; ++w) {
            float4 p = *(const float4*)(&part_s[w][wv][c0]);
            s.x += p.x; s.y += p.y; s.z += p.z; s.w += p.w;
        }
        float4 bb = *(const float4*)(bp + c0);
        float v0 = s.x + bb.x;
        float v1 = s.y + bb.y;
        float v2 = s.z + bb.z;
        float v3 = s.w + bb.w;
        float sm = v0 + v1 + v2 + v3;
        float sq = v0 * v0 + v1 * v1 + v2 * v2 + v3 * v3;
        #pragma unroll
        for (int off = 32; off > 0; off >>= 1) {
            sm += __shfl_xor(sm, off);
            sq += __shfl_xor(sq, off);
        }
        float mu   = sm * (1.0f / 256.0f);
        float var  = fmaxf(sq * (1.0f / 256.0f) - mu * mu, 0.0f);
        float rstd = 1.0f / sqrtf(var + 1e-5f);
        float4 gv = *(const float4*)(gvec + c0);
        float4 bv = *(const float4*)(bvec + c0);
        float4 o;
        o.x = (v0 - mu) * rstd * gv.x + bv.x;
        o.y = (v1 - mu) * rstd * gv.y + bv.y;
        o.z = (v2 - mu) * rstd * gv.z + bv.z;
        o.w = (v3 - mu) * rstd * gv.w + bv.w;
        *(float4*)(out + ((size_t)b * MAXK + slot) * DD + c0) = o;
    }
}

extern "C" void kernel_launch(void* const* d_in, const int* in_sizes, int n_in,
                              void* d_out, int out_size, void* d_ws, size_t ws_size,
                              hipStream_t stream) {
    const float* grid_emb = (const float*)d_in[0];
    const int*   grid     = (const int*)d_in[1];
    const float* srep     = (const float*)d_in[2];
    const float* W1v = (const float*)d_in[3];
    const float* b1v = (const float*)d_in[4];
    const float* W2v = (const float*)d_in[5];
    const float* b2v = (const float*)d_in[6];
    const float* Wpv = (const float*)d_in[7];
    const float* bpv = (const float*)d_in[8];
    const float* gv  = (const float*)d_in[9];
    const float* bv  = (const float*)d_in[10];
    const float* osv = (const float*)d_in[11];
    float* out = (float*)d_out;

    const int B  = in_sizes[1] / HW;
    const int KS = in_sizes[2] / (B * DD);

    hipLaunchKernelGGL(ccce_fused, dim3(B * 2), dim3(512), 0, stream,
                       grid_emb, grid, srep, W1v, b1v, W2v, b2v, Wpv, bpv,
                       gv, bv, osv, out, KS);
}

// Round 7
// 28.488 us; speedup vs baseline: 1.2678x; 1.0144x over previous
//
#include <hip/hip_runtime.h>
#include <math.h>

#define HH 30
#define WWID 30
#define HW 900
#define SENTV 900
#define DD 256
#define MAXK 16
#define A_LD 264

#define COMP(v, jj) ((jj) == 0 ? (v).x : (jj) == 1 ? (v).y : (jj) == 2 ? (v).z : (v).w)

__device__ __forceinline__ float gelu_exact(float x) {
    return 0.5f * x * (1.0f + erff(x * 0.70710678118654752440f));
}

// Split-K GEMM phase: wave wv owns k in [32wv, 32wv+32), 8 rows x 4 cols/thread.
// Software-pipelined: chunk c+1's 8 weight float4s issued before chunk c's FMAs.
// All 8 waves write partials to part[wv]; ONE barrier; caller sums the 8.
__device__ __forceinline__ void gemm_phase(
    const float (* __restrict__ Asrc)[A_LD],
    const float* __restrict__ Wm,
    float (* __restrict__ part)[8][DD],
    int wv, int c0)
{
    const int kbase = wv * 32;
    float acc[8][4];
    #pragma unroll
    for (int r = 0; r < 8; ++r) { acc[r][0] = 0.f; acc[r][1] = 0.f; acc[r][2] = 0.f; acc[r][3] = 0.f; }

    const float* wp = Wm + (size_t)kbase * DD + c0;
    float4 wc[8], wn[8];
    #pragma unroll
    for (int j = 0; j < 8; ++j) wc[j] = *(const float4*)(wp + (size_t)j * DD);

    #pragma unroll
    for (int ch = 0; ch < 4; ++ch) {
        if (ch < 3) {   // prefetch next weight chunk
            const float* wpn = wp + (size_t)((ch + 1) * 8) * DD;
            #pragma unroll
            for (int j = 0; j < 8; ++j) wn[j] = *(const float4*)(wpn + (size_t)j * DD);
        }
        float4 aA[8], aB[8];
        #pragma unroll
        for (int r = 0; r < 8; ++r) {
            aA[r] = *(const float4*)(&Asrc[r][kbase + ch * 8]);
            aB[r] = *(const float4*)(&Asrc[r][kbase + ch * 8 + 4]);
        }
        #pragma unroll
        for (int j = 0; j < 4; ++j) {
            #pragma unroll
            for (int r = 0; r < 8; ++r) {
                float av = COMP(aA[r], j);
                acc[r][0] += av * wc[j].x;
                acc[r][1] += av * wc[j].y;
                acc[r][2] += av * wc[j].z;
                acc[r][3] += av * wc[j].w;
            }
        }
        #pragma unroll
        for (int j = 0; j < 4; ++j) {
            #pragma unroll
            for (int r = 0; r < 8; ++r) {
                float av = COMP(aB[r], j);
                acc[r][0] += av * wc[4 + j].x;
                acc[r][1] += av * wc[4 + j].y;
                acc[r][2] += av * wc[4 + j].z;
                acc[r][3] += av * wc[4 + j].w;
            }
        }
        if (ch < 3) {
            #pragma unroll
            for (int j = 0; j < 8; ++j) wc[j] = wn[j];
        }
    }

    #pragma unroll
    for (int r = 0; r < 8; ++r)
        *(float4*)(&part[wv][r][c0]) = make_float4(acc[r][0], acc[r][1], acc[r][2], acc[r][3]);
    __syncthreads();
}

// Sum the 8 partials for (row=wv, cols c0..c0+3).
#define REDUCE8(sv)                                                           \
    float4 sv = *(const float4*)(&part_s[0][wv][c0]);                         \
    {                                                                         \
        _Pragma("unroll")                                                     \
        for (int w = 1; w < 8; ++w) {                                         \
            float4 p = *(const float4*)(&part_s[w][wv][c0]);                  \
            sv.x += p.x; sv.y += p.y; sv.z += p.z; sv.w += p.w;               \
        }                                                                     \
    }

__global__ __launch_bounds__(512, 2) void ccce_fused(
    const float* __restrict__ grid_emb,
    const int* __restrict__ grid,
    const float* __restrict__ structure_rep,
    const float* __restrict__ W1, const float* __restrict__ b1,
    const float* __restrict__ W2, const float* __restrict__ b2,
    const float* __restrict__ Wp, const float* __restrict__ bp,
    const float* __restrict__ gvec, const float* __restrict__ bvec,
    const float* __restrict__ ortho_scale,
    float* __restrict__ out, int KS)
{
    const int b   = blockIdx.x >> 1;
    const int h8  = blockIdx.x & 1;
    const int tid = threadIdx.x;
    const int tx  = tid & 63;
    const int wv  = tid >> 6;
    const int c0  = tx * 4;

    __shared__ int color_s[HW];
    __shared__ int lab_s[HW];
    __shared__ int slot_of[HW];
    __shared__ int root_s[MAXK];
    __shared__ int nroot_s;
    __shared__ int by0[MAXK], by1[MAXK], bx0[MAXK], bx1[MAXK];
    __shared__ __align__(16) float A1_s[8][A_LD];
    __shared__ __align__(16) float A2_s[8][A_LD];
    __shared__ __align__(16) float part_s[8][8][DD];  // 64 KB split-K partials
    __shared__ __align__(16) float sn_s[DD];
    __shared__ float red_s[4];

    // ---------- issue long-latency loads first ----------
    const int4* gp = (const int4*)(grid + (size_t)b * HW);
    int4 g;
    if (tid < 225) g = gp[tid];

    // structure_rep loads issued now; summed AFTER bbox (latency hides under CCL)
    const bool do_s = (tid < DD);
    float sl0 = 0.f, sl1 = 0.f, sl2 = 0.f, sl3 = 0.f, sl4 = 0.f, sl5 = 0.f, sl6 = 0.f, sl7 = 0.f;
    float s_gen = 0.f;
    {
        const float* sr = structure_rep + (size_t)b * KS * DD + tid;
        if (do_s) {
            if (KS == 8) {
                sl0 = sr[0 * DD]; sl1 = sr[1 * DD]; sl2 = sr[2 * DD]; sl3 = sr[3 * DD];
                sl4 = sr[4 * DD]; sl5 = sr[5 * DD]; sl6 = sr[6 * DD]; sl7 = sr[7 * DD];
            } else {
                for (int j = 0; j < KS; ++j) s_gen += sr[(size_t)j * DD];
            }
        }
    }

    // ---------- grid -> LDS, init labels ----------
    if (tid < 225) {
        int i = tid * 4;
        color_s[i + 0] = g.x; lab_s[i + 0] = (g.x > 0) ? (i + 0) : SENTV;
        color_s[i + 1] = g.y; lab_s[i + 1] = (g.y > 0) ? (i + 1) : SENTV;
        color_s[i + 2] = g.z; lab_s[i + 2] = (g.z > 0) ? (i + 2) : SENTV;
        color_s[i + 3] = g.w; lab_s[i + 3] = (g.w > 0) ? (i + 3) : SENTV;
    }
    __syncthreads();

    // ---------- cache per-cell neighbor-same-color masks (2 cells/thread) ----
    const int li0 = tid;
    const int li1 = tid + 512;
    int nm0 = 0, nm1 = 0;
    {
        int c = color_s[li0];
        if (c > 0) {
            int r = li0 / WWID, cc = li0 - (li0 / WWID) * WWID;
            nm0 = 16;
            if (r > 0        && color_s[li0 - WWID] == c) nm0 |= 1;
            if (r < HH - 1   && color_s[li0 + WWID] == c) nm0 |= 2;
            if (cc > 0       && color_s[li0 - 1]    == c) nm0 |= 4;
            if (cc < WWID-1  && color_s[li0 + 1]    == c) nm0 |= 8;
        }
    }
    if (li1 < HW) {
        int c = color_s[li1];
        if (c > 0) {
            int r = li1 / WWID, cc = li1 - (li1 / WWID) * WWID;
            nm1 = 16;
            if (r > 0        && color_s[li1 - WWID] == c) nm1 |= 1;
            if (r < HH - 1   && color_s[li1 + WWID] == c) nm1 |= 2;
            if (cc > 0       && color_s[li1 - 1]    == c) nm1 |= 4;
            if (cc < WWID-1  && color_s[li1 + 1]    == c) nm1 |= 8;
        }
    }

    // ---------- CCL: min-label relaxation, 1 barrier per sweep ----------
    for (;;) {
        int ch = 0;
        int m0 = 0, m1 = 0;
        if (nm0 & 16) {
            m0 = lab_s[li0];
            if (nm0 & 1) m0 = min(m0, lab_s[li0 - WWID]);
            if (nm0 & 2) m0 = min(m0, lab_s[li0 + WWID]);
            if (nm0 & 4) m0 = min(m0, lab_s[li0 - 1]);
            if (nm0 & 8) m0 = min(m0, lab_s[li0 + 1]);
        }
        if (nm1 & 16) {
            m1 = lab_s[li1];
            if (nm1 & 1) m1 = min(m1, lab_s[li1 - WWID]);
            if (nm1 & 2) m1 = min(m1, lab_s[li1 + WWID]);
            if (nm1 & 4) m1 = min(m1, lab_s[li1 - 1]);
            if (nm1 & 8) m1 = min(m1, lab_s[li1 + 1]);
        }
        if (nm0 & 16) m0 = min(m0, lab_s[m0]);
        if (nm1 & 16) m1 = min(m1, lab_s[m1]);
        if (nm0 & 16) m0 = min(m0, lab_s[m0]);
        if (nm1 & 16) m1 = min(m1, lab_s[m1]);
        if ((nm0 & 16) && m0 < lab_s[li0]) { lab_s[li0] = m0; ch = 1; }
        if ((nm1 & 16) && m1 < lab_s[li1]) { lab_s[li1] = m1; ch = 1; }
        if (__syncthreads_count(ch) == 0) break;
    }

    // ---------- roots (wave 0) || slot_of init (waves 1-7) ----------
    if (tid < 64) {
        int base = 0;
        for (int chk = 0; chk < 15; ++chk) {
            int cell = chk * 64 + tid;
            bool isr = (cell < HW) && (color_s[cell] > 0) && (lab_s[cell] == cell);
            unsigned long long mask = __ballot(isr);
            int rank = base + __popcll(mask & ((1ull << tid) - 1ull));
            if (isr && rank < MAXK) root_s[rank] = cell;
            base += __popcll(mask);
        }
        if (tid == 0) nroot_s = base;
    } else {
        for (int i = tid - 64; i < HW; i += 448) slot_of[i] = -1;
        if (tid >= 448 && tid < 448 + MAXK) {
            int k = tid - 448;
            by0[k] = HH; by1[k] = -1; bx0[k] = WWID; bx1[k] = -1;
        }
    }
    __syncthreads();

    const int nval = min(nroot_s, MAXK);
    if (tid < nval) slot_of[root_s[tid]] = tid;
    __syncthreads();

    // ---------- bbox pass: one slot_of lookup per fg cell ----------
    if (nm0 & 16) {
        int s = slot_of[lab_s[li0]];
        if (s >= 0) {
            int r = li0 / WWID, cc = li0 - (li0 / WWID) * WWID;
            atomicMin(&by0[s], r); atomicMax(&by1[s], r);
            atomicMin(&bx0[s], cc); atomicMax(&bx1[s], cc);
        }
    }
    if (nm1 & 16) {
        int s = slot_of[lab_s[li1]];
        if (s >= 0) {
            int r = li1 / WWID, cc = li1 - (li1 / WWID) * WWID;
            atomicMin(&by0[s], r); atomicMax(&by1[s], r);
            atomicMin(&bx0[s], cc); atomicMax(&bx1[s], cc);
        }
    }

    // ---------- structure mean reduce (loads issued at kernel start) ----------
    float s_mean = (KS == 8)
        ? (sl0 + sl1 + sl2 + sl3 + sl4 + sl5 + sl6 + sl7) * 0.125f
        : s_gen * (1.0f / (float)KS);
    {
        float ss = s_mean * s_mean;
        #pragma unroll
        for (int off = 32; off > 0; off >>= 1) ss += __shfl_xor(ss, off);
        if (tx == 0 && wv < 4) red_s[wv] = ss;
    }
    __syncthreads();   // bboxes + red_s final

    // ---------- sn + per-wave slot meta + pooling (8 loads in flight) -------
    if (do_s) {
        float nrm = sqrtf(red_s[0] + red_s[1] + red_s[2] + red_s[3]);
        sn_s[tid] = s_mean / fmaxf(nrm, 1e-8f);
    }
    const int slot = h8 * 8 + wv;
    const int v_ok = (slot < nval) ? 1 : 0;
    {
        float4 pv = make_float4(0.f, 0.f, 0.f, 0.f);
        int y = 0, x = 0, h = 1, w = 1, col = 0;
        if (v_ok) {
            y = by0[slot]; x = bx0[slot];
            h = by1[slot] + 1 - y; w = bx1[slot] + 1 - x;
            col = color_s[root_s[slot]];
            const int n = h * w;   // wave-uniform
            const float* bp_ = grid_emb + ((size_t)(b * HH + y) * WWID + x) * DD + c0;
            float4 sum = make_float4(0.f, 0.f, 0.f, 0.f);
            for (int base = 0; base < n; base += 8) {
                float4 v[8];
                #pragma unroll
                for (int t = 0; t < 8; ++t) {       // 8 independent loads in flight
                    int ii = base + t;
                    if (ii < n) {                    // wave-uniform predicate
                        int yy = ii / w, xx = ii - yy * w;
                        v[t] = *(const float4*)(bp_ + ((size_t)yy * WWID + xx) * DD);
                    }
                }
                #pragma unroll
                for (int t = 0; t < 8; ++t) {
                    int ii = base + t;
                    if (ii < n) { sum.x += v[t].x; sum.y += v[t].y; sum.z += v[t].z; sum.w += v[t].w; }
                }
            }
            float inv = 1.0f / (float)n;
            pv.x = sum.x * inv; pv.y = sum.y * inv; pv.z = sum.z * inv; pv.w = sum.w * inv;
        }
        *(float4*)(&A1_s[wv][c0]) = pv;
        if (tx < 8) {
            float f = 0.f;
            if (v_ok && tx < 5) {
                switch (tx) {
                    case 0: f = (float)col / 9.0f; break;
                    case 1: f = (float)x  / 30.0f; break;
                    case 2: f = (float)y  / 30.0f; break;
                    case 3: f = (float)w  / 30.0f; break;
                    case 4: f = (float)h  / 30.0f; break;
                }
            }
            A1_s[wv][256 + tx] = f;
        }
    }
    __syncthreads();   // A1 (comb) + sn ready

    // ================= GEMM1: hdn = gelu(comb @ W1 + b1) =================
    gemm_phase(A1_s, W1, part_s, wv, c0);
    {
        REDUCE8(s);
        #pragma unroll
        for (int j = 0; j < 5; ++j) {   // bbox-feature k's 256..260
            float a = A1_s[wv][256 + j];
            float4 wrow = *(const float4*)(W1 + (size_t)(256 + j) * DD + c0);
            s.x += a * wrow.x; s.y += a * wrow.y; s.z += a * wrow.z; s.w += a * wrow.w;
        }
        float4 bb = *(const float4*)(b1 + c0);
        float4 hv;
        hv.x = gelu_exact(s.x + bb.x);
        hv.y = gelu_exact(s.y + bb.y);
        hv.z = gelu_exact(s.z + bb.z);
        hv.w = gelu_exact(s.w + bb.w);
        *(float4*)(&A2_s[wv][c0]) = hv;
    }
    __syncthreads();

    // ================= GEMM2: obj = (hdn @ W2 + b2) * valid; ortho ========
    gemm_phase(A2_s, W2, part_s, wv, c0);
    {
        REDUCE8(s);
        float4 bb = *(const float4*)(b2 + c0);
        float vm = v_ok ? 1.f : 0.f;
        float o0 = (s.x + bb.x) * vm;
        float o1 = (s.y + bb.y) * vm;
        float o2 = (s.z + bb.z) * vm;
        float o3 = (s.w + bb.w) * vm;
        float4 snv = *(const float4*)(sn_s + c0);
        float p = o0 * snv.x + o1 * snv.y + o2 * snv.z + o3 * snv.w;
        #pragma unroll
        for (int off = 32; off > 0; off >>= 1) p += __shfl_xor(p, off);
        float osc = ortho_scale[0];
        float4 co;
        co.x = (o0 - p * snv.x) * osc;
        co.y = (o1 - p * snv.y) * osc;
        co.z = (o2 - p * snv.z) * osc;
        co.w = (o3 - p * snv.w) * osc;
        *(float4*)(&A1_s[wv][c0]) = co;
    }
    __syncthreads();

    // ================= GEMM3: co @ Wp + bp, LayerNorm =====================
    gemm_phase(A1_s, Wp, part_s, wv, c0);
    {
        REDUCE8(s);
        float4 bb = *(const float4*)(bp + c0);
        float v0 = s.x + bb.x;
        float v1 = s.y + bb.y;
        float v2 = s.z + bb.z;
        float v3 = s.w + bb.w;
        float sm = v0 + v1 + v2 + v3;
        float sq = v0 * v0 + v1 * v1 + v2 * v2 + v3 * v3;
        #pragma unroll
        for (int off = 32; off > 0; off >>= 1) {
            sm += __shfl_xor(sm, off);
            sq += __shfl_xor(sq, off);
        }
        float mu   = sm * (1.0f / 256.0f);
        float var  = fmaxf(sq * (1.0f / 256.0f) - mu * mu, 0.0f);
        float rstd = 1.0f / sqrtf(var + 1e-5f);
        float4 gv = *(const float4*)(gvec + c0);
        float4 bv = *(const float4*)(bvec + c0);
        float4 o;
        o.x = (v0 - mu) * rstd * gv.x + bv.x;
        o.y = (v1 - mu) * rstd * gv.y + bv.y;
        o.z = (v2 - mu) * rstd * gv.z + bv.z;
        o.w = (v3 - mu) * rstd * gv.w + bv.w;
        *(float4*)(out + ((size_t)b * MAXK + slot) * DD + c0) = o;
    }
}

extern "C" void kernel_launch(void* const* d_in, const int* in_sizes, int n_in,
                              void* d_out, int out_size, void* d_ws, size_t ws_size,
                              hipStream_t stream) {
    const float* grid_emb = (const float*)d_in[0];
    const int*   grid     = (const int*)d_in[1];
    const float* srep     = (const float*)d_in[2];
    const float* W1v = (const float*)d_in[3];
    const float* b1v = (const float*)d_in[4];
    const float* W2v = (const float*)d_in[5];
    const float* b2v = (const float*)d_in[6];
    const float* Wpv = (const float*)d_in[7];
    const float* bpv = (const float*)d_in[8];
    const float* gv  = (const float*)d_in[9];
    const float* bv  = (const float*)d_in[10];
    const float* osv = (const float*)d_in[11];
    float* out = (float*)d_out;

    const int B  = in_sizes[1] / HW;
    const int KS = in_sizes[2] / (B * DD);

    hipLaunchKernelGGL(ccce_fused, dim3(B * 2), dim3(512), 0, stream,
                       grid_emb, grid, srep, W1v, b1v, W2v, b2v, Wpv, bpv,
                       gv, bv, osv, out, KS);
}